// Round 1
// baseline (329.922 us; speedup 1.0000x reference)
//
#include <hip/hip_runtime.h>

// VQ-VAE quantize: z [32,64,64,64] NCHW fp32, codebook [512,64] fp32.
// out = quantized [32,64,64,64] NCHW (8388608 floats) ++ loss scalar (1 float).
// N = 131072 spatial vectors, D = 64, K = 512.

#define Bz   32
#define Dz   64
#define HWz  4096
#define Nz   (Bz * HWz)       // 131072
#define Kz   512
#define QSIZE ((size_t)Nz * Dz) // 8388608

// numpy pairwise_sum for 64 elements: 8 interleaved accumulators, then
// ((r0+r1)+(r2+r3))+((r4+r5)+(r6+r7)). Squares must round before add
// (numpy materializes v*v), so contraction is disabled in this block.
__device__ __forceinline__ float np_sumsq64(const float* v) {
#pragma clang fp contract(off)
    float r[8];
#pragma unroll
    for (int j = 0; j < 8; ++j) r[j] = v[j] * v[j];
#pragma unroll
    for (int i = 8; i < 64; i += 8) {
#pragma unroll
        for (int j = 0; j < 8; ++j) {
            float p = v[i + j] * v[i + j];
            r[j] = r[j] + p;
        }
    }
    return ((r[0] + r[1]) + (r[2] + r[3])) + ((r[4] + r[5]) + (r[6] + r[7]));
}

__global__ void vq_cnorm(const float* __restrict__ cb, float* __restrict__ cnorm) {
    int k = blockIdx.x * blockDim.x + threadIdx.x;
    if (k < Kz) {
        float v[64];
#pragma unroll
        for (int d = 0; d < 64; ++d) v[d] = cb[k * 64 + d];
        cnorm[k] = np_sumsq64(v);
    }
}

__global__ __launch_bounds__(256) void vq_main(
    const float* __restrict__ z, const float* __restrict__ cb,
    const float* __restrict__ cnorm, float* __restrict__ out,
    float* __restrict__ loss_accum) {
    const int n = blockIdx.x * 256 + threadIdx.x;
    const int b = n >> 12;     // n / 4096
    const int s = n & 4095;    // n % 4096

    // Load this spatial position's channel vector. Lanes cover consecutive s,
    // so each of the 64 loads is a fully-coalesced 256B wave transaction.
    const float* zp = z + (size_t)b * Dz * HWz + s;
    float zv[64];
#pragma unroll
    for (int d = 0; d < 64; ++d) zv[d] = zp[(size_t)d * HWz];

    const float znorm = np_sumsq64(zv);

    // dist_k = (znorm - 2*dot_k) + cnorm_k, same association order as the
    // reference expression. dot is a sequential-k fp32 FMA chain. Strict <
    // with ascending k == jnp.argmin first-min-wins.
    int best = 0;
    float bestd = __builtin_inff();
    for (int k0 = 0; k0 < Kz; k0 += 4) {
        const float* c0 = cb + (size_t)k0 * 64;  // wave-uniform address -> s_load
        float a0 = 0.f, a1 = 0.f, a2 = 0.f, a3 = 0.f;
#pragma unroll
        for (int d = 0; d < 64; ++d) {
            float zd = zv[d];
            a0 = __builtin_fmaf(zd, c0[d], a0);
            a1 = __builtin_fmaf(zd, c0[64 + d], a1);
            a2 = __builtin_fmaf(zd, c0[128 + d], a2);
            a3 = __builtin_fmaf(zd, c0[192 + d], a3);
        }
        float d0 = (znorm - 2.0f * a0) + cnorm[k0 + 0];
        float d1 = (znorm - 2.0f * a1) + cnorm[k0 + 1];
        float d2 = (znorm - 2.0f * a2) + cnorm[k0 + 2];
        float d3 = (znorm - 2.0f * a3) + cnorm[k0 + 3];
        if (d0 < bestd) { bestd = d0; best = k0 + 0; }
        if (d1 < bestd) { bestd = d1; best = k0 + 1; }
        if (d2 < bestd) { bestd = d2; best = k0 + 2; }
        if (d3 < bestd) { bestd = d3; best = k0 + 3; }
    }

    // Gather the chosen code, write straight-through output (NCHW), and
    // accumulate the squared error for the loss.
    const float* q = cb + (size_t)best * 64;
    float* op = out + (size_t)b * Dz * HWz + s;
    float lsum = 0.f;
#pragma unroll
    for (int d = 0; d < 64; ++d) {
        float qd = q[d];
        float err = zv[d] - qd;
        lsum += err * err;
        op[(size_t)d * HWz] = zv[d] + (qd - zv[d]);  // q_st, as written in ref
    }

    // Block-level loss reduction: wave shuffle, then LDS, then one atomic.
#pragma unroll
    for (int off = 32; off > 0; off >>= 1) lsum += __shfl_down(lsum, off, 64);
    __shared__ float wsum[4];
    const int lane = threadIdx.x & 63;
    const int wid = threadIdx.x >> 6;
    if (lane == 0) wsum[wid] = lsum;
    __syncthreads();
    if (threadIdx.x == 0) {
        float t = (wsum[0] + wsum[1]) + (wsum[2] + wsum[3]);
        atomicAdd(loss_accum, t);
    }
}

__global__ void vq_finalize(const float* __restrict__ loss_accum,
                            float* __restrict__ out_loss) {
    float X = loss_accum[0] / (float)QSIZE;
    out_loss[0] = X + 0.25f * X;  // embed_loss + 0.25 * commit_loss
}

extern "C" void kernel_launch(void* const* d_in, const int* in_sizes, int n_in,
                              void* d_out, int out_size, void* d_ws, size_t ws_size,
                              hipStream_t stream) {
    const float* z  = (const float*)d_in[0];
    const float* cb = (const float*)d_in[1];
    float* out = (float*)d_out;
    float* wsf = (float*)d_ws;
    // wsf[0] = loss accumulator (zeroed every call); wsf[16..527] = cnorm[512].
    hipMemsetAsync(d_ws, 0, 4, stream);
    vq_cnorm<<<1, 512, 0, stream>>>(cb, wsf + 16);
    vq_main<<<Nz / 256, 256, 0, stream>>>(z, cb, wsf + 16, out, wsf);
    vq_finalize<<<1, 1, 0, stream>>>(wsf, out + QSIZE);
}